// Round 5
// baseline (525.786 us; speedup 1.0000x reference)
//
#include <hip/hip_runtime.h>
#include <hip/hip_cooperative_groups.h>

namespace cg = cooperative_groups;

constexpr int TT   = 8192;   // nb_territories
constexpr int HH   = 4096;   // hidden size
constexpr int NACT = 65536;  // action pairs
constexpr int NTH  = 256;
constexpr int NBMAX = 1024;  // upper bound on cooperative grid (4 blocks/CU)

typedef float f32x4 __attribute__((ext_vector_type(4)));  // native vec for NT stores

// deterministic block-wide sum; returns the same value to ALL threads
__device__ __forceinline__ float block_reduce(float v, float* s, int t)
{
#pragma unroll
    for (int off = 32; off; off >>= 1) v += __shfl_down(v, off, 64);
    if ((t & 63) == 0) s[t >> 6] = v;
    __syncthreads();
    float r = s[0] + s[1] + s[2] + s[3];
    __syncthreads();                       // protect s[] reuse
    return r;
}

// ---------------------------------------------------------------------------
// Cooperative fused kernel, grid-size-agnostic (nb = gridDim.x, any value).
//  P1: x = tanh(Win@p + bin)  (rows strided)  +  NT zero-fill of out
//  P2: th = tanh([Wo;Wd]@x + [bo;bd])  (rows strided)
//  P3: u = exp(torig[o]*tdest[d] - 1); claim zeroed slot via atomicExch;
//      unique claimant adds u to block partial. (exp(-1000-m)==0 in fp32 =>
//      all non-action softmax entries are exactly 0; shift m'=1 is valid.)
//  P4: redundant deterministic reduce of partials -> invZ; rescale writes
//      (idempotent across duplicate actions).
// ---------------------------------------------------------------------------
__global__ __launch_bounds__(256, 4) void k_fused(
    const int*   __restrict__ pa,
    const float* __restrict__ p,
    const float* __restrict__ Win, const float* __restrict__ bin,
    const float* __restrict__ Wo,  const float* __restrict__ bo,
    const float* __restrict__ Wd,  const float* __restrict__ bd,
    float* __restrict__ out,
    float* __restrict__ x, float* __restrict__ th, float* __restrict__ partial)
{
    cg::grid_group grid = cg::this_grid();
    const int nb = gridDim.x;
    const int b  = blockIdx.x;
    const int t  = threadIdx.x;
    __shared__ float s[4];

    // ---------------- Phase 1: input GEMV + zero-fill ----------------
    {
        const float4* __restrict__ pv = reinterpret_cast<const float4*>(p);
        for (int row = b; row < HH; row += nb) {
            const float4* __restrict__ Wr =
                reinterpret_cast<const float4*>(Win + (size_t)row * TT);
            float acc = 0.f;
#pragma unroll
            for (int i = 0; i < TT / 4 / NTH; ++i) {       // 8 iters
                float4 w = Wr[i * NTH + t];
                float4 q = pv[i * NTH + t];
                acc += w.x * q.x + w.y * q.y + w.z * q.z + w.w * q.w;
            }
            float sum = block_reduce(acc, s, t);
            if (t == 0) x[row] = tanhf(sum + bin[row]);
        }
        // zero-fill 16M float4 with NT stores (don't pollute L2)
        f32x4* __restrict__ o4 = reinterpret_cast<f32x4*>(out);
        const f32x4 z = {0.f, 0.f, 0.f, 0.f};
        const int n4 = TT * (TT / 4);                      // 16,777,216
        const int gstride = nb * NTH;
        for (int i = b * NTH + t; i < n4; i += gstride)
            __builtin_nontemporal_store(z, &o4[i]);
    }
    grid.sync();

    // ---------------- Phase 2: both head GEMVs ----------------
    {
        const float4* __restrict__ xv = reinterpret_cast<const float4*>(x);
        for (int r = b; r < 2 * TT; r += nb) {
            const float* W; const float* bb; int rr;
            if (r < TT) { W = Wo; bb = bo; rr = r; }
            else        { W = Wd; bb = bd; rr = r - TT; }
            const float4* __restrict__ Wr =
                reinterpret_cast<const float4*>(W + (size_t)rr * HH);
            float acc = 0.f;
#pragma unroll
            for (int i = 0; i < HH / 4 / NTH; ++i) {       // 4 iters
                float4 w = Wr[i * NTH + t];
                float4 q = xv[i * NTH + t];
                acc += w.x * q.x + w.y * q.y + w.z * q.z + w.w * q.w;
            }
            float sum = block_reduce(acc, s, t);
            if (t == 0) th[r] = tanhf(sum + bb[rr]);
        }
    }
    grid.sync();

    // ---------------- Phase 3: scatter + claim + block partials ----------------
    {
        float c = 0.f;
        const int gstride = nb * NTH;
        for (int i = b * NTH + t; i < NACT; i += gstride) {
            const int o = pa[2 * i];
            const int d = pa[2 * i + 1];
            const float v = th[o] * th[TT + d];
            const float u = expf(v - 1.0f);
            float old = atomicExch(out + ((size_t)o * TT + d), u);
            if (old == 0.0f) c += u;                       // unique positions once
        }
        float bc = block_reduce(c, s, t);
        if (t == 0) partial[b] = bc;
    }
    grid.sync();

    // ---------------- Phase 4: reduce partials, finalize ----------------
    {
        float ps = 0.f;
        for (int i = t; i < nb; i += NTH) ps += partial[i];
        const float invZ = 1.0f / block_reduce(ps, s, t);  // same in all threads
        const int gstride = nb * NTH;
        for (int i = b * NTH + t; i < NACT; i += gstride) {
            const int o = pa[2 * i];
            const int d = pa[2 * i + 1];
            const float v = th[o] * th[TT + d];
            out[(size_t)o * TT + d] = expf(v - 1.0f) * invZ;
        }
    }
}

// ------------------- sequential fallback (known-good R1 path) -------------------
__global__ __launch_bounds__(256) void k_gemv_in(
    const float* __restrict__ W, const float* __restrict__ p,
    const float* __restrict__ b, float* __restrict__ x)
{
    const int row = blockIdx.x;
    const int t   = threadIdx.x;
    const float4* __restrict__ Wr = reinterpret_cast<const float4*>(W + (size_t)row * TT);
    const float4* __restrict__ pv = reinterpret_cast<const float4*>(p);
    float acc = 0.f;
#pragma unroll
    for (int i = 0; i < TT / 4 / 256; ++i) {
        float4 w = Wr[i * 256 + t];
        float4 q = pv[i * 256 + t];
        acc += w.x * q.x + w.y * q.y + w.z * q.z + w.w * q.w;
    }
    __shared__ float s[4];
    float sum = block_reduce(acc, s, t);
    if (t == 0) x[row] = tanhf(sum + b[row]);
}

__global__ __launch_bounds__(256) void k_gemv_heads(
    const float* __restrict__ Wo, const float* __restrict__ bo,
    const float* __restrict__ Wd, const float* __restrict__ bd,
    const float* __restrict__ x, float* __restrict__ th)
{
    const int bid = blockIdx.x;
    const int t   = threadIdx.x;
    const float* W; const float* b; int r;
    if (bid < TT) { W = Wo; b = bo; r = bid; }
    else          { W = Wd; b = bd; r = bid - TT; }
    const float4* __restrict__ Wr = reinterpret_cast<const float4*>(W + (size_t)r * HH);
    const float4* __restrict__ xv = reinterpret_cast<const float4*>(x);
    float acc = 0.f;
#pragma unroll
    for (int i = 0; i < HH / 4 / 256; ++i) {
        float4 w = Wr[i * 256 + t];
        float4 q = xv[i * 256 + t];
        acc += w.x * q.x + w.y * q.y + w.z * q.z + w.w * q.w;
    }
    __shared__ float s[4];
    float sum = block_reduce(acc, s, t);
    if (t == 0) th[bid] = tanhf(sum + b[r]);
}

__global__ __launch_bounds__(256) void k_scatter(
    const int* __restrict__ pa, const float* __restrict__ th,
    float* __restrict__ out, float* __restrict__ partial)
{
    const int i = blockIdx.x * 256 + threadIdx.x;
    const int o = pa[2 * i];
    const int d = pa[2 * i + 1];
    const float v = th[o] * th[TT + d];
    const float u = expf(v - 1.0f);
    float old = atomicExch(out + ((size_t)o * TT + d), u);
    float c = (old == 0.0f) ? u : 0.0f;
    __shared__ float s[4];
    float bc = block_reduce(c, s, threadIdx.x);
    if (threadIdx.x == 0) partial[blockIdx.x] = bc;
}

__global__ __launch_bounds__(256) void k_finalize(
    const int* __restrict__ pa, const float* __restrict__ th,
    const float* __restrict__ partial, float* __restrict__ out)
{
    __shared__ float s[4];
    const float invZ = 1.0f / block_reduce(partial[threadIdx.x], s, threadIdx.x);
    const int i = blockIdx.x * 256 + threadIdx.x;
    const int o = pa[2 * i];
    const int d = pa[2 * i + 1];
    const float v = th[o] * th[TT + d];
    out[(size_t)o * TT + d] = expf(v - 1.0f) * invZ;
}

// ---------------------------------------------------------------------------
extern "C" void kernel_launch(void* const* d_in, const int* in_sizes, int n_in,
                              void* d_out, int out_size, void* d_ws, size_t ws_size,
                              hipStream_t stream)
{
    const int*   pa  = (const int*)  d_in[0];
    const float* p   = (const float*)d_in[1];
    const float* Win = (const float*)d_in[2];
    const float* bin = (const float*)d_in[3];
    const float* Wo  = (const float*)d_in[4];
    const float* bo  = (const float*)d_in[5];
    const float* Wd  = (const float*)d_in[6];
    const float* bd  = (const float*)d_in[7];
    float* out = (float*)d_out;

    float* x       = (float*)d_ws;        // [HH]
    float* th      = x + HH;              // [2*TT]
    float* partial = th + 2 * TT;         // [NBMAX]

    // Size the cooperative grid from the runtime's own occupancy math
    // (host-side queries: deterministic, graph-capture-safe).
    int dev = 0;
    (void)hipGetDevice(&dev);
    int nCU = 0;
    (void)hipDeviceGetAttribute(&nCU, hipDeviceAttributeMultiprocessorCount, dev);
    int maxB = 0;
    (void)hipOccupancyMaxActiveBlocksPerMultiprocessor(&maxB, k_fused, NTH, 0);

    long cap = (long)maxB * (long)nCU;
    int nb = (cap < NBMAX) ? (int)cap : NBMAX;

    bool coop_ok = false;
    if (nb >= 64) {
        void* args[] = { (void*)&pa, (void*)&p, (void*)&Win, (void*)&bin,
                         (void*)&Wo, (void*)&bo, (void*)&Wd, (void*)&bd,
                         (void*)&out, (void*)&x, (void*)&th, (void*)&partial };
        hipError_t le = hipLaunchCooperativeKernel(
            reinterpret_cast<void*>(k_fused), dim3(nb), dim3(NTH), args, 0, stream);
        coop_ok = (le == hipSuccess);
    }

    if (!coop_ok) {  // known-good sequential path
        hipMemsetAsync(out, 0, (size_t)out_size * sizeof(float), stream);
        k_gemv_in   <<<HH,         NTH, 0, stream>>>(Win, p, bin, x);
        k_gemv_heads<<<2 * TT,     NTH, 0, stream>>>(Wo, bo, Wd, bd, x, th);
        k_scatter   <<<NACT / NTH, NTH, 0, stream>>>(pa, th, out, partial);
        k_finalize  <<<NACT / NTH, NTH, 0, stream>>>(pa, th, partial, out);
    }
}

// Round 6
// 128.591 us; speedup vs baseline: 4.0888x; 4.0888x over previous
//
#include <hip/hip_runtime.h>

constexpr int TT   = 8192;   // nb_territories
constexpr int HH   = 4096;   // hidden size
constexpr int NACT = 65536;  // action pairs
constexpr int NTH  = 256;

typedef float f32x4 __attribute__((ext_vector_type(4)));  // native vec for NT stores

// deterministic block-wide sum; returns the same value to ALL threads
__device__ __forceinline__ float block_reduce(float v, float* s, int t)
{
#pragma unroll
    for (int off = 32; off; off >>= 1) v += __shfl_down(v, off, 64);
    if ((t & 63) == 0) s[t >> 6] = v;
    __syncthreads();
    float r = s[0] + s[1] + s[2] + s[3];
    __syncthreads();
    return r;
}

// ---------------------------------------------------------------------------
// K1: x[row] = tanh(Win[row,:] @ p + bin[row])  (row = blockIdx.x, 4096 blocks)
//     + zero-fill 192 MB of out (3072 float4 per block, NT stores so the dead
//       zero stream doesn't evict L3-resident weights).
// Traffic: 128 MB R + 192 MB W = 320 MB.
// ---------------------------------------------------------------------------
__global__ __launch_bounds__(256) void k_gemv_in_fill(
    const float* __restrict__ W, const float* __restrict__ p,
    const float* __restrict__ b, float* __restrict__ x, float* __restrict__ out)
{
    const int row = blockIdx.x;
    const int t   = threadIdx.x;
    const float4* __restrict__ Wr = reinterpret_cast<const float4*>(W + (size_t)row * TT);
    const float4* __restrict__ pv = reinterpret_cast<const float4*>(p);
    float acc = 0.f;
#pragma unroll
    for (int i = 0; i < TT / 4 / NTH; ++i) {   // 8 iters
        float4 w = Wr[i * NTH + t];
        float4 q = pv[i * NTH + t];
        acc += w.x * q.x + w.y * q.y + w.z * q.z + w.w * q.w;
    }
    __shared__ float s[4];
    float sum = block_reduce(acc, s, t);
    if (t == 0) x[row] = tanhf(sum + b[row]);

    // zero-fill slice: 3072 float4 = 48 KB per block, 12 per thread
    f32x4* __restrict__ o4 = reinterpret_cast<f32x4*>(out);
    const f32x4 z = {0.f, 0.f, 0.f, 0.f};
    const size_t base = (size_t)row * 3072;
#pragma unroll
    for (int i = 0; i < 12; ++i)
        __builtin_nontemporal_store(z, &o4[base + i * NTH + t]);
}

// ---------------------------------------------------------------------------
// K2: th[r] = tanh([Wo;Wd][r,:] @ x + [bo;bd][r])  (r = blockIdx.x, 16384 blocks)
//     + zero-fill the remaining 64 MB of out (256 float4 per block).
// Traffic: 256 MB R + 64 MB W = 320 MB.
// ---------------------------------------------------------------------------
__global__ __launch_bounds__(256) void k_heads_fill(
    const float* __restrict__ Wo, const float* __restrict__ bo,
    const float* __restrict__ Wd, const float* __restrict__ bd,
    const float* __restrict__ x, float* __restrict__ th, float* __restrict__ out)
{
    const int r = blockIdx.x;
    const int t = threadIdx.x;
    const float* W; const float* bb; int rr;
    if (r < TT) { W = Wo; bb = bo; rr = r; }
    else        { W = Wd; bb = bd; rr = r - TT; }
    const float4* __restrict__ Wr = reinterpret_cast<const float4*>(W + (size_t)rr * HH);
    const float4* __restrict__ xv = reinterpret_cast<const float4*>(x);
    float acc = 0.f;
#pragma unroll
    for (int i = 0; i < HH / 4 / NTH; ++i) {   // 4 iters
        float4 w = Wr[i * NTH + t];
        float4 q = xv[i * NTH + t];
        acc += w.x * q.x + w.y * q.y + w.z * q.z + w.w * q.w;
    }
    __shared__ float s[4];
    float sum = block_reduce(acc, s, t);
    if (t == 0) th[r] = tanhf(sum + bb[rr]);

    // zero-fill slice: float4 indices [12582912 + r*256, +256)
    f32x4* __restrict__ o4 = reinterpret_cast<f32x4*>(out);
    const f32x4 z = {0.f, 0.f, 0.f, 0.f};
    __builtin_nontemporal_store(z, &o4[12582912 + (size_t)r * NTH + t]);
}

// ---------------------------------------------------------------------------
// K3: u = exp(torig[o]*tdest[d] - 1); claim zeroed slot via atomicExch; the
// unique claimant adds u to the block partial. (exp(-1000-m)==0 in fp32 =>
// all non-action softmax entries are exactly 0; shift m'=1 valid since v<=1.)
// ---------------------------------------------------------------------------
__global__ __launch_bounds__(256) void k_scatter(
    const int* __restrict__ pa, const float* __restrict__ th,
    float* __restrict__ out, float* __restrict__ partial)
{
    const int i = blockIdx.x * NTH + threadIdx.x;
    const int o = pa[2 * i];
    const int d = pa[2 * i + 1];
    const float v = th[o] * th[TT + d];
    const float u = expf(v - 1.0f);
    float old = atomicExch(out + ((size_t)o * TT + d), u);
    float c = (old == 0.0f) ? u : 0.0f;
    __shared__ float s[4];
    float bc = block_reduce(c, s, threadIdx.x);
    if (threadIdx.x == 0) partial[blockIdx.x] = bc;
}

// ---------------------------------------------------------------------------
// K4: every block deterministically reduces the 256 partials -> invZ; write
// out = u * invZ (idempotent across duplicate actions).
// ---------------------------------------------------------------------------
__global__ __launch_bounds__(256) void k_finalize(
    const int* __restrict__ pa, const float* __restrict__ th,
    const float* __restrict__ partial, float* __restrict__ out)
{
    __shared__ float s[4];
    const float invZ = 1.0f / block_reduce(partial[threadIdx.x], s, threadIdx.x);
    const int i = blockIdx.x * NTH + threadIdx.x;
    const int o = pa[2 * i];
    const int d = pa[2 * i + 1];
    const float v = th[o] * th[TT + d];
    out[(size_t)o * TT + d] = expf(v - 1.0f) * invZ;
}

// ---------------------------------------------------------------------------
extern "C" void kernel_launch(void* const* d_in, const int* in_sizes, int n_in,
                              void* d_out, int out_size, void* d_ws, size_t ws_size,
                              hipStream_t stream)
{
    const int*   pa  = (const int*)  d_in[0];  // possible_actions [NACT,2] int32
    const float* p   = (const float*)d_in[1];  // presence [TT]
    const float* Win = (const float*)d_in[2];  // [HH,TT]
    const float* bin = (const float*)d_in[3];  // [HH]
    const float* Wo  = (const float*)d_in[4];  // [TT,HH]
    const float* bo  = (const float*)d_in[5];  // [TT]
    const float* Wd  = (const float*)d_in[6];  // [TT,HH]
    const float* bd  = (const float*)d_in[7];  // [TT]
    float* out = (float*)d_out;

    float* x       = (float*)d_ws;        // [HH]
    float* th      = x + HH;              // [2*TT]
    float* partial = th + 2 * TT;         // [256]

    k_gemv_in_fill<<<HH,         NTH, 0, stream>>>(Win, p, bin, x, out);
    k_heads_fill  <<<2 * TT,     NTH, 0, stream>>>(Wo, bo, Wd, bd, x, th, out);
    k_scatter     <<<NACT / NTH, NTH, 0, stream>>>(pa, th, out, partial);
    k_finalize    <<<NACT / NTH, NTH, 0, stream>>>(pa, th, partial, out);
}